// Round 8
// baseline (288.270 us; speedup 1.0000x reference)
//
#include <hip/hip_runtime.h>
#include <hip/hip_bf16.h>
#include <stdint.h>

typedef unsigned short u16;
typedef __attribute__((ext_vector_type(8))) short bf16x8;
typedef __attribute__((ext_vector_type(4))) float f32x4;
typedef __attribute__((ext_vector_type(16))) float f32x16;

static __device__ inline u16 f2bf(float f) {
  union { float f; uint32_t u; } v; v.f = f;
  uint32_t u = v.u;
  u += 0x7fffu + ((u >> 16) & 1);   // RNE
  return (u16)(u >> 16);
}

// fast 2^x -> single v_exp_f32
static __device__ inline float fast_exp2(float x) {
#if __has_builtin(__builtin_amdgcn_exp2f)
  return __builtin_amdgcn_exp2f(x);
#else
  return __expf(x * 0.6931471805599453f);
#endif
}

// pack two fp32 -> packed bf16x2
static __device__ inline uint32_t pack_bf16(float lo, float hi) {
#if __has_builtin(__builtin_amdgcn_cvt_pk_bf16_f32)
  typedef __attribute__((ext_vector_type(2))) __bf16 bf16x2_t;
  bf16x2_t r = __builtin_amdgcn_cvt_pk_bf16_f32(lo, hi);
  union { bf16x2_t v; uint32_t u; } c; c.v = r;
  return c.u;
#else
  union { float f; uint32_t u; } a, b;
  a.f = lo; b.f = hi;
  uint32_t ua = a.u + 0x8000u;
  uint32_t ub = b.u + 0x8000u;
  return __builtin_amdgcn_perm(ub, ua, 0x07060302u);
#endif
}

// cross-half exchange: x = [a_lo | b_lo_from_partner], y = [a_hi_from_partner | b_hi]
static __device__ __forceinline__ void plswap(uint32_t a, uint32_t b,
                                              uint32_t& x, uint32_t& y) {
#if __has_builtin(__builtin_amdgcn_permlane32_swap)
  auto r = __builtin_amdgcn_permlane32_swap(a, b, false, false);
  x = (uint32_t)r[0]; y = (uint32_t)r[1];
#else
  int h = (threadIdx.x & 63) >> 5;
  uint32_t pa = (uint32_t)__shfl_xor((int)a, 32, 64);
  uint32_t pb = (uint32_t)__shfl_xor((int)b, 32, 64);
  x = h ? pb : a;
  y = h ? b : pa;
#endif
}

// async global->LDS, 16B per lane; LDS dest must be lane-contiguous (base + lane*16)
static __device__ __forceinline__ void load_lds_128(const u16* g, u16* l) {
  __builtin_amdgcn_global_load_lds((const __attribute__((address_space(1))) void*)g,
                                   (__attribute__((address_space(3))) void*)l,
                                   16, 0, 0);
}

// ---------------- fused prep: cast z fp32->bf16  +  weight transpose/cast ----------
__global__ __launch_bounds__(256) void prep_kernel(const float* __restrict__ zsrc,
                                                   u16* __restrict__ zdst,
                                                   const float* __restrict__ wq,
                                                   const float* __restrict__ wk,
                                                   const float* __restrict__ wv,
                                                   const float* __restrict__ wo,
                                                   u16* __restrict__ bqkv,
                                                   u16* __restrict__ wot) {
  const int bid = blockIdx.x;
  const int tid = threadIdx.x;
  if (bid < 8192) {
    int i = bid * 256 + tid;
    float4 v = reinterpret_cast<const float4*>(zsrc)[i];
    uint2 o;
    o.x = pack_bf16(v.x, v.y);
    o.y = pack_bf16(v.z, v.w);
    reinterpret_cast<uint2*>(zdst)[i] = o;
    return;
  }
  const int w = bid - 8192;
  const int z = w >> 10;
  const int rem = w & 1023;
  const float* src = (z == 0) ? wq : (z == 1) ? wk : (z == 2) ? wv : wo;
  u16* dst = (z < 3) ? (bqkv + (size_t)z * 1024 * 1024) : wot;
  __shared__ float tile[32][33];
  const int c0 = (rem & 31) * 32, r0 = (rem >> 5) * 32;
  const int tx = tid & 31, ty = tid >> 5;
#pragma unroll
  for (int i = 0; i < 32; i += 8)
    tile[ty + i][tx] = src[(size_t)(r0 + ty + i) * 1024 + c0 + tx];
  __syncthreads();
#pragma unroll
  for (int i = 0; i < 32; i += 8)
    dst[(size_t)(c0 + ty + i) * 1024 + r0 + tx] = f2bf(tile[tx][ty + i]);
}

// ---------------- GEMM m97 128x64 tile (output projection): C = A @ Bt^T + bias ----
// grid (16,64) = 1024 blocks = 4 blocks/CU = 16 waves/CU. LDS 12 KB, acc[4][2].
__global__ __launch_bounds__(256) void gemm_bt64_kernel(
    const u16* __restrict__ A, const u16* __restrict__ Bt,
    float* __restrict__ outC, const float* __restrict__ bias) {
  const int Kd = 1024;
  const int n0 = blockIdx.x * 64;
  const int m0 = blockIdx.y * 128;
  __shared__ __align__(16) u16 Asm[128 * 32];
  __shared__ __align__(16) u16 Bsm[64 * 32];
  const int tid = threadIdx.x;
  const int wave = tid >> 6, lane = tid & 63;
  const int quad = lane >> 4, l15 = lane & 15;
  const int wm = (wave >> 1) * 64, wn = (wave & 1) * 32;

  const int c0 = wave * 128 + lane;     // A chunks 0..511 (two per thread)
  const int c1 = c0 + 64;
  const int r0 = c0 >> 2, p0 = (c0 & 3) * 8;
  const int r1 = c1 >> 2, p1 = (c1 & 3) * 8;
  const int cB = tid;                   // B chunks 0..255 (one per thread)
  const int rB = cB >> 2, pB = (cB & 3) * 8;

  const u16* Ab = A + (size_t)m0 * Kd;
  const u16* Bb = Bt + (size_t)n0 * Kd;

  f32x4 acc[4][2] = {};

  for (int k0 = 0; k0 < Kd; k0 += 32) {
    __syncthreads();
    load_lds_128(Ab + (size_t)r0 * Kd + k0 + p0, Asm + c0 * 8);
    load_lds_128(Ab + (size_t)r1 * Kd + k0 + p1, Asm + c1 * 8);
    load_lds_128(Bb + (size_t)rB * Kd + k0 + pB, Bsm + cB * 8);
    __syncthreads();
    bf16x8 af[4], bf[2];
#pragma unroll
    for (int i = 0; i < 4; i++)
      af[i] = *reinterpret_cast<const bf16x8*>(Asm + (wm + i * 16 + l15) * 32 + quad * 8);
#pragma unroll
    for (int i = 0; i < 2; i++)
      bf[i] = *reinterpret_cast<const bf16x8*>(Bsm + (wn + i * 16 + l15) * 32 + quad * 8);
#pragma unroll
    for (int mi = 0; mi < 4; mi++)
#pragma unroll
      for (int ni = 0; ni < 2; ni++)
        acc[mi][ni] = __builtin_amdgcn_mfma_f32_16x16x32_bf16(af[mi], bf[ni], acc[mi][ni], 0, 0, 0);
  }

#pragma unroll
  for (int mi = 0; mi < 4; mi++)
#pragma unroll
    for (int ni = 0; ni < 2; ni++) {
      int n = n0 + wn + ni * 16 + l15;
      float bv = bias[n];
#pragma unroll
      for (int r = 0; r < 4; r++) {
        int m = m0 + wm + mi * 16 + quad * 4 + r;
        outC[(size_t)m * 1024 + n] = acc[mi][ni][r] + bv;
      }
    }
}

// ---------------- 256x256 8-phase GEMM (QKV projection, MODE-0 epilogue) ------------
// (round-6 configuration: single launch dim3(12,32), rule-#18 sched_barrier fix)
__global__ __launch_bounds__(512, 2) void gemm256_kernel(
    const u16* __restrict__ A, const u16* __restrict__ Bt,
    u16* __restrict__ outQ, u16* __restrict__ outK, u16* __restrict__ outVt) {
  const int tid = threadIdx.x;
  const int lane = tid & 63;
  const int wave = tid >> 6;
  const int quad = lane >> 4, l15 = lane & 15;
  const int e15 = l15 & 7;
  const int wm = wave >> 2;     // 0..1 M-half
  const int wn = wave & 3;      // 0..3 N-slice

  // XCD-aware bijective swizzle (grid 12x32 = 384 blocks, 384 % 8 == 0)
  unsigned lin = blockIdx.y * gridDim.x + blockIdx.x;
  unsigned nwg = gridDim.x * gridDim.y;
  lin = (lin & 7u) * (nwg >> 3) + (lin >> 3);
  const int bx = lin % gridDim.x, by = lin / gridDim.x;
  const int n0 = bx * 256, m0 = by * 256;

  __shared__ __align__(16) u16 AsmL[2][16384];   // [buf][half*8192 + row*64 + slot*8]
  __shared__ __align__(16) u16 BsmL[2][16384];
  u16* const As_[2] = {&AsmL[0][0], &AsmL[1][0]};
  u16* const Bs_[2] = {&BsmL[0][0], &BsmL[1][0]};

  const u16* Abase = A + (size_t)m0 * 1024;
  const u16* Bbase = Bt + (size_t)n0 * 1024;

  const int awoff = wm * 8192;
  const int bwoff = (wn >> 1) * 8192 + (wn & 1) * 4096;

  f32x4 acc[8][4] = {};
  bf16x8 af[4][2], bfr[4][2];

#define STG_HALF(ldsp, gp)                                                      \
  {                                                                             \
    const int cs0 = tid, cs1 = tid + 512;                                       \
    const int r0_ = cs0 >> 3, g0_ = (((cs0 & 7) ^ (r0_ & 7)) << 3);             \
    const int r1_ = cs1 >> 3, g1_ = (((cs1 & 7) ^ (r1_ & 7)) << 3);             \
    load_lds_128((gp) + (size_t)r0_ * 1024 + g0_, (ldsp) + cs0 * 8);            \
    load_lds_128((gp) + (size_t)r1_ * 1024 + g1_, (ldsp) + cs1 * 8);            \
  }

#define PHB() do { asm volatile("" ::: "memory"); __builtin_amdgcn_s_barrier(); \
                   asm volatile("" ::: "memory"); } while (0)
#define LGKM0() do { asm volatile("s_waitcnt lgkmcnt(0)" ::: "memory");         \
                     __builtin_amdgcn_sched_barrier(0); } while (0)
#define VMC8()  asm volatile("s_waitcnt vmcnt(8)" ::: "memory")

#define RD_A(mb, B)                                                             \
  _Pragma("unroll") for (int x = 0; x < 4; x++)                                 \
  _Pragma("unroll") for (int kk = 0; kk < 2; kk++)                              \
    af[x][kk] = *reinterpret_cast<const bf16x8*>(                               \
        As_[B] + awoff + (((mb) + x) * 16 + l15) * 64 + (((quad + kk * 4) ^ e15) << 3));

#define RD_B(nb, B)                                                             \
  _Pragma("unroll") for (int x = 0; x < 2; x++)                                 \
  _Pragma("unroll") for (int kk = 0; kk < 2; kk++)                              \
    bfr[(nb) + x][kk] = *reinterpret_cast<const bf16x8*>(                       \
        Bs_[B] + bwoff + (((nb) + x) * 16 + l15) * 64 + (((quad + kk * 4) ^ e15) << 3));

#define MM(mb, nb)                                                              \
  _Pragma("unroll") for (int kk = 0; kk < 2; kk++)                              \
  _Pragma("unroll") for (int x = 0; x < 4; x++)                                 \
  _Pragma("unroll") for (int y = 0; y < 2; y++)                                 \
    acc[(mb) + x][(nb) + y] = __builtin_amdgcn_mfma_f32_16x16x32_bf16(          \
        af[x][kk], bfr[(nb) + y][kk], acc[(mb) + x][(nb) + y], 0, 0, 0);

#define TILE4(B, KS)                                                            \
  RD_A(0, B); RD_B(0, B);                                                       \
  PHB(); LGKM0(); __builtin_amdgcn_s_setprio(1); MM(0, 0);                      \
  __builtin_amdgcn_s_setprio(0); PHB();                                         \
  RD_B(2, B);                                                                   \
  PHB(); LGKM0(); __builtin_amdgcn_s_setprio(1); MM(0, 2);                      \
  __builtin_amdgcn_s_setprio(0); PHB();                                         \
  RD_A(4, B);                                                                   \
  STG_HALF(Bs_[B], Bbase + (KS)); STG_HALF(Bs_[B] + 8192, Bbase + 128 * 1024 + (KS)); \
  PHB(); LGKM0(); __builtin_amdgcn_s_setprio(1); MM(4, 0);                      \
  __builtin_amdgcn_s_setprio(0); PHB();                                         \
  STG_HALF(As_[B], Abase + (KS)); STG_HALF(As_[B] + 8192, Abase + 128 * 1024 + (KS)); \
  PHB(); __builtin_amdgcn_s_setprio(1); MM(4, 2);                               \
  __builtin_amdgcn_s_setprio(0); VMC8(); PHB();

  // prologue: tile0 -> buf0 (oldest 8 loads), tile1 -> buf1
  STG_HALF(As_[0], Abase);      STG_HALF(As_[0] + 8192, Abase + 128 * 1024);
  STG_HALF(Bs_[0], Bbase);      STG_HALF(Bs_[0] + 8192, Bbase + 128 * 1024);
  STG_HALF(As_[1], Abase + 64); STG_HALF(As_[1] + 8192, Abase + 128 * 1024 + 64);
  STG_HALF(Bs_[1], Bbase + 64); STG_HALF(Bs_[1] + 8192, Bbase + 128 * 1024 + 64);
  VMC8(); PHB();

#pragma unroll 1
  for (int it = 0; it < 8; ++it) {
    int t2 = it * 2 + 2; if (t2 > 15) t2 = 15;   // clamped: tail re-stages valid
    int t3 = it * 2 + 3; if (t3 > 15) t3 = 15;   // data into dead slots (never read)
    const int k2 = t2 * 64, k3 = t3 * 64;
    TILE4(0, k2);
    TILE4(1, k3);
  }

  // -------- MODE-0 epilogue: split Q / K / Vt --------
  const int which = (n0 + wn * 64) >> 10;
#pragma unroll
  for (int mi = 0; mi < 8; mi++)
#pragma unroll
    for (int ni = 0; ni < 4; ni++) {
      int n = n0 + wn * 64 + ni * 16 + l15;
      int hn = n & 1023;
      int hh = hn >> 6, dim = hn & 63;
      if (which == 2) {
        int m = m0 + wm * 128 + mi * 16 + quad * 4;
        int b = m >> 11, tok = m & 2047;
        uint2 pk;
        pk.x = pack_bf16(acc[mi][ni][0], acc[mi][ni][1]);
        pk.y = pack_bf16(acc[mi][ni][2], acc[mi][ni][3]);
        *reinterpret_cast<uint2*>(outVt + ((size_t)(b * 16 + hh) * 64 + dim) * 2048 + tok) = pk;
      } else {
        u16* dst = (which == 0) ? outQ : outK;
        float qscale = (which == 0) ? 0.1803368801111204f : 1.0f; // 0.125*log2(e)
#pragma unroll
        for (int r = 0; r < 4; r++) {
          int m = m0 + wm * 128 + mi * 16 + quad * 4 + r;
          int b = m >> 11, tok = m & 2047;
          dst[(((size_t)(b * 16 + hh)) * 2048 + tok) * 64 + dim] = f2bf(acc[mi][ni][r] * qscale);
        }
      }
    }
#undef STG_HALF
#undef PHB
#undef LGKM0
#undef VMC8
#undef RD_A
#undef RD_B
#undef MM
#undef TILE4
}

// ---------------- flash attention: 3-buffer rotation, counted vmcnt ----------------
// Round-6 structure (batched QK + setprio, measured 88.8 us) with the T4 fix:
// __syncthreads drained vmcnt(0) every tile -- each wave waited for the DMA it
// issued THAT tile (~900 cyc HBM latency, exposed tail = the ~20% that
// MfmaUtil+VALUBusy leaves uncovered). Now: 3-deep K/V rotation, prefetch t+2
// at tile t, loop-head `vmcnt(4)` (own tile-t loads landed; tile-t+1's 4 stay
// in flight) + raw s_barrier. WAR ledger: buf (r+2)%3 was read at t-1; those
// reads retire before their MFMAs (compiler lgkm waits) -> before the t
// barrier -> DMA issued after it is safe. Tail uniform via clamped dummy
// prefetch (re-stages tile 0 into a dead buffer; L2-hit, never read).
// sched_barrier(0) after the inline vmcnt (rule #18).
__global__ __launch_bounds__(256, 2) void attn_kernel(const u16* __restrict__ Q,
                                                      const u16* __restrict__ K,
                                                      const u16* __restrict__ Vt,
                                                      u16* __restrict__ Oout) {
  const int bh = blockIdx.x;
  const int q0 = blockIdx.y * 256;
  const int tid = threadIdx.x;
  const int wave = tid >> 6, lane = tid & 63;
  const int l31 = lane & 31, h = lane >> 5;
  const int e = l31 & 7;

  __shared__ __align__(16) u16 Kb3[3][4096];   // [buf][64 rows][64], swizzled chunks
  __shared__ __align__(16) u16 Vb3[3][4096];

  const u16* Qg = Q + ((size_t)bh * 2048 + q0 + wave * 64) * 64;
  const u16* Kg = K + (size_t)bh * 2048 * 64;
  const u16* Vg = Vt + (size_t)bh * 64 * 2048;

  bf16x8 qf[2][4];
#pragma unroll
  for (int j = 0; j < 2; j++)
#pragma unroll
    for (int dc = 0; dc < 4; dc++)
      qf[j][dc] = *reinterpret_cast<const bf16x8*>(
          Qg + (size_t)(j * 32 + l31) * 64 + dc * 16 + h * 8);

  const int s0 = tid, s1 = tid + 256;
  const int sr0 = s0 >> 3, sg0 = ((s0 & 7) ^ (sr0 & 7)) * 8;
  const int sr1 = s1 >> 3, sg1 = ((s1 & 7) ^ (sr1 & 7)) * 8;

#define STAGE(ktv, buf_)                                                           \
  load_lds_128(Kg + (size_t)((ktv) + sr0) * 64 + sg0, &Kb3[buf_][s0 * 8]);         \
  load_lds_128(Kg + (size_t)((ktv) + sr1) * 64 + sg1, &Kb3[buf_][s1 * 8]);         \
  load_lds_128(Vg + (size_t)sr0 * 2048 + (ktv) + sg0, &Vb3[buf_][s0 * 8]);         \
  load_lds_128(Vg + (size_t)sr1 * 2048 + (ktv) + sg1, &Vb3[buf_][s1 * 8]);

  // prologue: tiles 0,1 in flight (8 loads/wave outstanding)
  STAGE(0, 0);
  STAGE(64, 1);

  float ls[2][2] = {};
  f32x16 oacc[2][2] = {};   // [j][dt]
  int rbuf = 0;

  for (int kt = 0; kt < 2048; kt += 64) {
    // own tile-t loads landed (oldest 4 of 8); next tile's 4 stay in flight
    asm volatile("s_waitcnt vmcnt(4)" ::: "memory");
    __builtin_amdgcn_sched_barrier(0);
    asm volatile("" ::: "memory");
    __builtin_amdgcn_s_barrier();
    asm volatile("" ::: "memory");

    const u16* uK = &Kb3[rbuf][0];
    const u16* uV = &Vb3[rbuf][0];

    // prefetch tile t+2 into buf (rbuf+2)%3 (dummy tile-0 restage at tail)
    {
      int pbuf = rbuf + 2; if (pbuf >= 3) pbuf -= 3;
      int ktp = kt + 128; if (ktp >= 2048) ktp = 0;
      STAGE(ktp, pbuf);
    }

    bf16x8 kfr[2][4], vfr[2][2][2];
#pragma unroll
    for (int kb = 0; kb < 2; kb++)
#pragma unroll
      for (int dc = 0; dc < 4; dc++)
        kfr[kb][dc] = *reinterpret_cast<const bf16x8*>(
            uK + (kb * 32 + l31) * 64 + (((2 * dc + h) ^ e) * 8));
#pragma unroll
    for (int dt = 0; dt < 2; dt++)
#pragma unroll
      for (int kb = 0; kb < 2; kb++)
#pragma unroll
        for (int kc = 0; kc < 2; kc++)
          vfr[dt][kb][kc] = *reinterpret_cast<const bf16x8*>(
              uV + (dt * 32 + l31) * 64 + (((4 * kb + 2 * kc + h) ^ e) * 8));

    // ---- batched QK^T: all 16 MFMAs, 4 independent chains ----
    f32x16 s4[4];   // g = kb*2 + j  (static indexing only)
    __builtin_amdgcn_s_setprio(1);
#pragma unroll
    for (int g = 0; g < 4; g++) {
      const int kb = g >> 1, j = g & 1;
      f32x16 s = {};
#pragma unroll
      for (int dc = 0; dc < 4; dc++)
        s = __builtin_amdgcn_mfma_f32_32x32x16_bf16(kfr[kb][dc], qf[j][dc], s, 0, 0, 0);
      s4[g] = s;
    }
    __builtin_amdgcn_s_setprio(0);

    // ---- softmax + PV per group; group g overlaps group g-1's PV ----
#pragma unroll
    for (int g = 0; g < 4; g++) {
      const int kb = g >> 1, j = g & 1;
      float p[16];
#pragma unroll
      for (int i = 0; i < 16; i++) p[i] = fast_exp2(s4[g][i]);
#pragma unroll
      for (int i = 0; i < 16; i += 2) { ls[j][0] += p[i]; ls[j][1] += p[i + 1]; }
      uint32_t pk[4][2];
#pragma unroll
      for (int rq = 0; rq < 4; rq++) {
        pk[rq][0] = pack_bf16(p[rq * 4 + 0], p[rq * 4 + 1]);
        pk[rq][1] = pack_bf16(p[rq * 4 + 2], p[rq * 4 + 3]);
      }
      uint4 b0, b1;
      plswap(pk[0][0], pk[1][0], b0.x, b0.z);
      plswap(pk[0][1], pk[1][1], b0.y, b0.w);
      plswap(pk[2][0], pk[3][0], b1.x, b1.z);
      plswap(pk[2][1], pk[3][1], b1.y, b1.w);
      union { uint4 u; bf16x8 v; } bf0, bf1;
      bf0.u = b0; bf1.u = b1;
      __builtin_amdgcn_s_setprio(1);
#pragma unroll
      for (int dt = 0; dt < 2; dt++) {
        oacc[j][dt] = __builtin_amdgcn_mfma_f32_32x32x16_bf16(vfr[dt][kb][0], bf0.v, oacc[j][dt], 0, 0, 0);
        oacc[j][dt] = __builtin_amdgcn_mfma_f32_32x32x16_bf16(vfr[dt][kb][1], bf1.v, oacc[j][dt], 0, 0, 0);
      }
      __builtin_amdgcn_s_setprio(0);
    }

    rbuf = (rbuf == 2) ? 0 : rbuf + 1;
  }
#undef STAGE

  const int b = bh >> 4, hd = bh & 15;
  u16* dst = Oout + (size_t)b * 2048 * 1024 + (size_t)hd * 64;
#pragma unroll
  for (int j = 0; j < 2; j++) {
    float lsum = ls[j][0] + ls[j][1];
    lsum += __shfl_xor(lsum, 32, 64);
    float inv = __builtin_amdgcn_rcpf(lsum);
    const size_t qrow = (size_t)(q0 + wave * 64 + j * 32 + l31) * 1024;
#pragma unroll
    for (int dt = 0; dt < 2; dt++)
#pragma unroll
      for (int rq = 0; rq < 4; rq++) {
        uint2 o;
        o.x = pack_bf16(oacc[j][dt][rq * 4 + 0] * inv, oacc[j][dt][rq * 4 + 1] * inv);
        o.y = pack_bf16(oacc[j][dt][rq * 4 + 2] * inv, oacc[j][dt][rq * 4 + 3] * inv);
        *reinterpret_cast<uint2*>(dst + qrow + dt * 32 + rq * 8 + h * 4) = o;
      }
  }
}

extern "C" void kernel_launch(void* const* d_in, const int* in_sizes, int n_in,
                              void* d_out, int out_size, void* d_ws, size_t ws_size,
                              hipStream_t stream) {
  (void)in_sizes; (void)n_in; (void)out_size; (void)ws_size;
  const float* z  = (const float*)d_in[0];
  const float* wq = (const float*)d_in[1];
  const float* wk = (const float*)d_in[2];
  const float* wv = (const float*)d_in[3];
  const float* wo = (const float*)d_in[4];
  const float* bo = (const float*)d_in[5];
  float* out = (float*)d_out;

  // workspace layout (72 MiB):
  char* ws = (char*)d_ws;
  u16* zb   = (u16*)(ws);                          // 16 MiB  z bf16 [8192][1024]; reused as attn_out
  u16* bqkv = (u16*)(ws + (16ull << 20));          // 6 MiB   W_qkv^T [3072][1024]
  u16* wot  = (u16*)(ws + (22ull << 20));          // 2 MiB   W_o^T   [1024][1024]
  u16* Qb   = (u16*)(ws + (24ull << 20));          // 16 MiB  [64][2048][64]
  u16* Kb   = (u16*)(ws + (40ull << 20));          // 16 MiB  [64][2048][64]
  u16* Vtb  = (u16*)(ws + (56ull << 20));          // 16 MiB  [64][64][2048] (written by GEMM)
  u16* Ob   = zb;                                  // attn_out [8192][1024]

  prep_kernel<<<12288, 256, 0, stream>>>(z, zb, wq, wk, wv, wo, bqkv, wot);
  gemm256_kernel<<<dim3(12, 32), 512, 0, stream>>>(zb, bqkv, Qb, Kb, Vtb);
  attn_kernel<<<dim3(64, 8), 256, 0, stream>>>(Qb, Kb, Vtb, Ob);
  gemm_bt64_kernel<<<dim3(16, 64), 256, 0, stream>>>(Ob, wot, out, bo);
}

// Round 9
// 285.483 us; speedup vs baseline: 1.0098x; 1.0098x over previous
//
#include <hip/hip_runtime.h>
#include <hip/hip_bf16.h>
#include <stdint.h>

typedef unsigned short u16;
typedef __attribute__((ext_vector_type(8))) short bf16x8;
typedef __attribute__((ext_vector_type(4))) float f32x4;
typedef __attribute__((ext_vector_type(16))) float f32x16;

static __device__ inline u16 f2bf(float f) {
  union { float f; uint32_t u; } v; v.f = f;
  uint32_t u = v.u;
  u += 0x7fffu + ((u >> 16) & 1);   // RNE
  return (u16)(u >> 16);
}

// fast 2^x -> single v_exp_f32
static __device__ inline float fast_exp2(float x) {
#if __has_builtin(__builtin_amdgcn_exp2f)
  return __builtin_amdgcn_exp2f(x);
#else
  return __expf(x * 0.6931471805599453f);
#endif
}

// pack two fp32 -> packed bf16x2
static __device__ inline uint32_t pack_bf16(float lo, float hi) {
#if __has_builtin(__builtin_amdgcn_cvt_pk_bf16_f32)
  typedef __attribute__((ext_vector_type(2))) __bf16 bf16x2_t;
  bf16x2_t r = __builtin_amdgcn_cvt_pk_bf16_f32(lo, hi);
  union { bf16x2_t v; uint32_t u; } c; c.v = r;
  return c.u;
#else
  union { float f; uint32_t u; } a, b;
  a.f = lo; b.f = hi;
  uint32_t ua = a.u + 0x8000u;
  uint32_t ub = b.u + 0x8000u;
  return __builtin_amdgcn_perm(ub, ua, 0x07060302u);
#endif
}

// cross-half exchange: x = [a_lo | b_lo_from_partner], y = [a_hi_from_partner | b_hi]
static __device__ __forceinline__ void plswap(uint32_t a, uint32_t b,
                                              uint32_t& x, uint32_t& y) {
#if __has_builtin(__builtin_amdgcn_permlane32_swap)
  auto r = __builtin_amdgcn_permlane32_swap(a, b, false, false);
  x = (uint32_t)r[0]; y = (uint32_t)r[1];
#else
  int h = (threadIdx.x & 63) >> 5;
  uint32_t pa = (uint32_t)__shfl_xor((int)a, 32, 64);
  uint32_t pb = (uint32_t)__shfl_xor((int)b, 32, 64);
  x = h ? pb : a;
  y = h ? b : pa;
#endif
}

// async global->LDS, 16B per lane; LDS dest must be lane-contiguous (base + lane*16)
static __device__ __forceinline__ void load_lds_128(const u16* g, u16* l) {
  __builtin_amdgcn_global_load_lds((const __attribute__((address_space(1))) void*)g,
                                   (__attribute__((address_space(3))) void*)l,
                                   16, 0, 0);
}

// ---------------- fused prep: cast z fp32->bf16  +  weight transpose/cast ----------
__global__ __launch_bounds__(256) void prep_kernel(const float* __restrict__ zsrc,
                                                   u16* __restrict__ zdst,
                                                   const float* __restrict__ wq,
                                                   const float* __restrict__ wk,
                                                   const float* __restrict__ wv,
                                                   const float* __restrict__ wo,
                                                   u16* __restrict__ bqkv,
                                                   u16* __restrict__ wot) {
  const int bid = blockIdx.x;
  const int tid = threadIdx.x;
  if (bid < 8192) {
    int i = bid * 256 + tid;
    float4 v = reinterpret_cast<const float4*>(zsrc)[i];
    uint2 o;
    o.x = pack_bf16(v.x, v.y);
    o.y = pack_bf16(v.z, v.w);
    reinterpret_cast<uint2*>(zdst)[i] = o;
    return;
  }
  const int w = bid - 8192;
  const int z = w >> 10;
  const int rem = w & 1023;
  const float* src = (z == 0) ? wq : (z == 1) ? wk : (z == 2) ? wv : wo;
  u16* dst = (z < 3) ? (bqkv + (size_t)z * 1024 * 1024) : wot;
  __shared__ float tile[32][33];
  const int c0 = (rem & 31) * 32, r0 = (rem >> 5) * 32;
  const int tx = tid & 31, ty = tid >> 5;
#pragma unroll
  for (int i = 0; i < 32; i += 8)
    tile[ty + i][tx] = src[(size_t)(r0 + ty + i) * 1024 + c0 + tx];
  __syncthreads();
#pragma unroll
  for (int i = 0; i < 32; i += 8)
    dst[(size_t)(c0 + ty + i) * 1024 + r0 + tx] = f2bf(tile[tx][ty + i]);
}

// ---------------- GEMM m97 128x64 tile (output projection): C = A @ Bt^T + bias ----
// grid (16,64) = 1024 blocks = 4 blocks/CU = 16 waves/CU. LDS 12 KB, acc[4][2].
__global__ __launch_bounds__(256) void gemm_bt64_kernel(
    const u16* __restrict__ A, const u16* __restrict__ Bt,
    float* __restrict__ outC, const float* __restrict__ bias) {
  const int Kd = 1024;
  const int n0 = blockIdx.x * 64;
  const int m0 = blockIdx.y * 128;
  __shared__ __align__(16) u16 Asm[128 * 32];
  __shared__ __align__(16) u16 Bsm[64 * 32];
  const int tid = threadIdx.x;
  const int wave = tid >> 6, lane = tid & 63;
  const int quad = lane >> 4, l15 = lane & 15;
  const int wm = (wave >> 1) * 64, wn = (wave & 1) * 32;

  const int c0 = wave * 128 + lane;     // A chunks 0..511 (two per thread)
  const int c1 = c0 + 64;
  const int r0 = c0 >> 2, p0 = (c0 & 3) * 8;
  const int r1 = c1 >> 2, p1 = (c1 & 3) * 8;
  const int cB = tid;                   // B chunks 0..255 (one per thread)
  const int rB = cB >> 2, pB = (cB & 3) * 8;

  const u16* Ab = A + (size_t)m0 * Kd;
  const u16* Bb = Bt + (size_t)n0 * Kd;

  f32x4 acc[4][2] = {};

  for (int k0 = 0; k0 < Kd; k0 += 32) {
    __syncthreads();
    load_lds_128(Ab + (size_t)r0 * Kd + k0 + p0, Asm + c0 * 8);
    load_lds_128(Ab + (size_t)r1 * Kd + k0 + p1, Asm + c1 * 8);
    load_lds_128(Bb + (size_t)rB * Kd + k0 + pB, Bsm + cB * 8);
    __syncthreads();
    bf16x8 af[4], bf[2];
#pragma unroll
    for (int i = 0; i < 4; i++)
      af[i] = *reinterpret_cast<const bf16x8*>(Asm + (wm + i * 16 + l15) * 32 + quad * 8);
#pragma unroll
    for (int i = 0; i < 2; i++)
      bf[i] = *reinterpret_cast<const bf16x8*>(Bsm + (wn + i * 16 + l15) * 32 + quad * 8);
#pragma unroll
    for (int mi = 0; mi < 4; mi++)
#pragma unroll
      for (int ni = 0; ni < 2; ni++)
        acc[mi][ni] = __builtin_amdgcn_mfma_f32_16x16x32_bf16(af[mi], bf[ni], acc[mi][ni], 0, 0, 0);
  }

#pragma unroll
  for (int mi = 0; mi < 4; mi++)
#pragma unroll
    for (int ni = 0; ni < 2; ni++) {
      int n = n0 + wn + ni * 16 + l15;
      float bv = bias[n];
#pragma unroll
      for (int r = 0; r < 4; r++) {
        int m = m0 + wm + mi * 16 + quad * 4 + r;
        outC[(size_t)m * 1024 + n] = acc[mi][ni][r] + bv;
      }
    }
}

// ---------------- 256x256 8-phase GEMM (QKV projection, MODE-0 epilogue) ------------
// (round-6 configuration: single launch dim3(12,32), rule-#18 sched_barrier fix)
__global__ __launch_bounds__(512, 2) void gemm256_kernel(
    const u16* __restrict__ A, const u16* __restrict__ Bt,
    u16* __restrict__ outQ, u16* __restrict__ outK, u16* __restrict__ outVt) {
  const int tid = threadIdx.x;
  const int lane = tid & 63;
  const int wave = tid >> 6;
  const int quad = lane >> 4, l15 = lane & 15;
  const int e15 = l15 & 7;
  const int wm = wave >> 2;     // 0..1 M-half
  const int wn = wave & 3;      // 0..3 N-slice

  // XCD-aware bijective swizzle (grid 12x32 = 384 blocks, 384 % 8 == 0)
  unsigned lin = blockIdx.y * gridDim.x + blockIdx.x;
  unsigned nwg = gridDim.x * gridDim.y;
  lin = (lin & 7u) * (nwg >> 3) + (lin >> 3);
  const int bx = lin % gridDim.x, by = lin / gridDim.x;
  const int n0 = bx * 256, m0 = by * 256;

  __shared__ __align__(16) u16 AsmL[2][16384];   // [buf][half*8192 + row*64 + slot*8]
  __shared__ __align__(16) u16 BsmL[2][16384];
  u16* const As_[2] = {&AsmL[0][0], &AsmL[1][0]};
  u16* const Bs_[2] = {&BsmL[0][0], &BsmL[1][0]};

  const u16* Abase = A + (size_t)m0 * 1024;
  const u16* Bbase = Bt + (size_t)n0 * 1024;

  const int awoff = wm * 8192;
  const int bwoff = (wn >> 1) * 8192 + (wn & 1) * 4096;

  f32x4 acc[8][4] = {};
  bf16x8 af[4][2], bfr[4][2];

#define STG_HALF(ldsp, gp)                                                      \
  {                                                                             \
    const int cs0 = tid, cs1 = tid + 512;                                       \
    const int r0_ = cs0 >> 3, g0_ = (((cs0 & 7) ^ (r0_ & 7)) << 3);             \
    const int r1_ = cs1 >> 3, g1_ = (((cs1 & 7) ^ (r1_ & 7)) << 3);             \
    load_lds_128((gp) + (size_t)r0_ * 1024 + g0_, (ldsp) + cs0 * 8);            \
    load_lds_128((gp) + (size_t)r1_ * 1024 + g1_, (ldsp) + cs1 * 8);            \
  }

#define PHB() do { asm volatile("" ::: "memory"); __builtin_amdgcn_s_barrier(); \
                   asm volatile("" ::: "memory"); } while (0)
#define LGKM0() do { asm volatile("s_waitcnt lgkmcnt(0)" ::: "memory");         \
                     __builtin_amdgcn_sched_barrier(0); } while (0)
#define VMC8()  asm volatile("s_waitcnt vmcnt(8)" ::: "memory")

#define RD_A(mb, B)                                                             \
  _Pragma("unroll") for (int x = 0; x < 4; x++)                                 \
  _Pragma("unroll") for (int kk = 0; kk < 2; kk++)                              \
    af[x][kk] = *reinterpret_cast<const bf16x8*>(                               \
        As_[B] + awoff + (((mb) + x) * 16 + l15) * 64 + (((quad + kk * 4) ^ e15) << 3));

#define RD_B(nb, B)                                                             \
  _Pragma("unroll") for (int x = 0; x < 2; x++)                                 \
  _Pragma("unroll") for (int kk = 0; kk < 2; kk++)                              \
    bfr[(nb) + x][kk] = *reinterpret_cast<const bf16x8*>(                       \
        Bs_[B] + bwoff + (((nb) + x) * 16 + l15) * 64 + (((quad + kk * 4) ^ e15) << 3));

#define MM(mb, nb)                                                              \
  _Pragma("unroll") for (int kk = 0; kk < 2; kk++)                              \
  _Pragma("unroll") for (int x = 0; x < 4; x++)                                 \
  _Pragma("unroll") for (int y = 0; y < 2; y++)                                 \
    acc[(mb) + x][(nb) + y] = __builtin_amdgcn_mfma_f32_16x16x32_bf16(          \
        af[x][kk], bfr[(nb) + y][kk], acc[(mb) + x][(nb) + y], 0, 0, 0);

#define TILE4(B, KS)                                                            \
  RD_A(0, B); RD_B(0, B);                                                       \
  PHB(); LGKM0(); __builtin_amdgcn_s_setprio(1); MM(0, 0);                      \
  __builtin_amdgcn_s_setprio(0); PHB();                                         \
  RD_B(2, B);                                                                   \
  PHB(); LGKM0(); __builtin_amdgcn_s_setprio(1); MM(0, 2);                      \
  __builtin_amdgcn_s_setprio(0); PHB();                                         \
  RD_A(4, B);                                                                   \
  STG_HALF(Bs_[B], Bbase + (KS)); STG_HALF(Bs_[B] + 8192, Bbase + 128 * 1024 + (KS)); \
  PHB(); LGKM0(); __builtin_amdgcn_s_setprio(1); MM(4, 0);                      \
  __builtin_amdgcn_s_setprio(0); PHB();                                         \
  STG_HALF(As_[B], Abase + (KS)); STG_HALF(As_[B] + 8192, Abase + 128 * 1024 + (KS)); \
  PHB(); __builtin_amdgcn_s_setprio(1); MM(4, 2);                               \
  __builtin_amdgcn_s_setprio(0); VMC8(); PHB();

  // prologue: tile0 -> buf0 (oldest 8 loads), tile1 -> buf1
  STG_HALF(As_[0], Abase);      STG_HALF(As_[0] + 8192, Abase + 128 * 1024);
  STG_HALF(Bs_[0], Bbase);      STG_HALF(Bs_[0] + 8192, Bbase + 128 * 1024);
  STG_HALF(As_[1], Abase + 64); STG_HALF(As_[1] + 8192, Abase + 128 * 1024 + 64);
  STG_HALF(Bs_[1], Bbase + 64); STG_HALF(Bs_[1] + 8192, Bbase + 128 * 1024 + 64);
  VMC8(); PHB();

#pragma unroll 1
  for (int it = 0; it < 8; ++it) {
    int t2 = it * 2 + 2; if (t2 > 15) t2 = 15;   // clamped: tail re-stages valid
    int t3 = it * 2 + 3; if (t3 > 15) t3 = 15;   // data into dead slots (never read)
    const int k2 = t2 * 64, k3 = t3 * 64;
    TILE4(0, k2);
    TILE4(1, k3);
  }

  // -------- MODE-0 epilogue: split Q / K / Vt --------
  const int which = (n0 + wn * 64) >> 10;
#pragma unroll
  for (int mi = 0; mi < 8; mi++)
#pragma unroll
    for (int ni = 0; ni < 4; ni++) {
      int n = n0 + wn * 64 + ni * 16 + l15;
      int hn = n & 1023;
      int hh = hn >> 6, dim = hn & 63;
      if (which == 2) {
        int m = m0 + wm * 128 + mi * 16 + quad * 4;
        int b = m >> 11, tok = m & 2047;
        uint2 pk;
        pk.x = pack_bf16(acc[mi][ni][0], acc[mi][ni][1]);
        pk.y = pack_bf16(acc[mi][ni][2], acc[mi][ni][3]);
        *reinterpret_cast<uint2*>(outVt + ((size_t)(b * 16 + hh) * 64 + dim) * 2048 + tok) = pk;
      } else {
        u16* dst = (which == 0) ? outQ : outK;
        float qscale = (which == 0) ? 0.1803368801111204f : 1.0f; // 0.125*log2(e)
#pragma unroll
        for (int r = 0; r < 4; r++) {
          int m = m0 + wm * 128 + mi * 16 + quad * 4 + r;
          int b = m >> 11, tok = m & 2047;
          dst[(((size_t)(b * 16 + hh)) * 2048 + tok) * 64 + dim] = f2bf(acc[mi][ni][r] * qscale);
        }
      }
    }
#undef STG_HALF
#undef PHB
#undef LGKM0
#undef VMC8
#undef RD_A
#undef RD_B
#undef MM
#undef TILE4
}

// ---------------- flash attention: 64 q/wave, batched QK, KVBLK=128 ----------------
// Round-6 structure (batched QK + setprio, measured 88.8 us; round-8's manual
// vmcnt/barrier pipeline REGRESSED to 99.5 -- compiler-managed sync wins) with
// one change: two 64-key sub-tiles per iteration, ONE __syncthreads per 128
// keys (16 barriers+drains instead of 32). DMA for the next 128-key tile is
// issued between sub0's frag reads and compute, giving it sub0+sub1's full
// compute phase to land before the end-of-iteration drain. Key order, ls/oacc
// accumulation order, and all numerics identical to round 6.
__global__ __launch_bounds__(256, 2) void attn_kernel(const u16* __restrict__ Q,
                                                      const u16* __restrict__ K,
                                                      const u16* __restrict__ Vt,
                                                      u16* __restrict__ Oout) {
  const int bh = blockIdx.x;
  const int q0 = blockIdx.y * 256;
  const int tid = threadIdx.x;
  const int wave = tid >> 6, lane = tid & 63;
  const int l31 = lane & 31, h = lane >> 5;
  const int e = l31 & 7;

  __shared__ __align__(16) u16 Kb2[2][2][4096];   // [dbuf][sub][64 rows][64] swizzled
  __shared__ __align__(16) u16 Vb2[2][2][4096];

  const u16* Qg = Q + ((size_t)bh * 2048 + q0 + wave * 64) * 64;
  const u16* Kg = K + (size_t)bh * 2048 * 64;
  const u16* Vg = Vt + (size_t)bh * 64 * 2048;

  bf16x8 qf[2][4];
#pragma unroll
  for (int j = 0; j < 2; j++)
#pragma unroll
    for (int dc = 0; dc < 4; dc++)
      qf[j][dc] = *reinterpret_cast<const bf16x8*>(
          Qg + (size_t)(j * 32 + l31) * 64 + dc * 16 + h * 8);

  const int s0 = tid, s1 = tid + 256;
  const int sr0 = s0 >> 3, sg0 = ((s0 & 7) ^ (sr0 & 7)) * 8;
  const int sr1 = s1 >> 3, sg1 = ((s1 & 7) ^ (sr1 & 7)) * 8;

#define STAGE_SUB(ktv, buf_, sub_)                                                 \
  load_lds_128(Kg + (size_t)((ktv) + sr0) * 64 + sg0, &Kb2[buf_][sub_][s0 * 8]);   \
  load_lds_128(Kg + (size_t)((ktv) + sr1) * 64 + sg1, &Kb2[buf_][sub_][s1 * 8]);   \
  load_lds_128(Vg + (size_t)sr0 * 2048 + (ktv) + sg0, &Vb2[buf_][sub_][s0 * 8]);   \
  load_lds_128(Vg + (size_t)sr1 * 2048 + (ktv) + sg1, &Vb2[buf_][sub_][s1 * 8]);

  STAGE_SUB(0, 0, 0);
  STAGE_SUB(64, 0, 1);
  __syncthreads();   // tile 0 (both subs) resident

  float ls[2][2] = {};
  f32x16 oacc[2][2] = {};   // [j][dt]
  int cur = 0;

  for (int kt = 0; kt < 2048; kt += 128) {
#pragma unroll
    for (int sub = 0; sub < 2; sub++) {
      const u16* uK = &Kb2[cur][sub][0];
      const u16* uV = &Vb2[cur][sub][0];

      bf16x8 kfr[2][4], vfr[2][2][2];
#pragma unroll
      for (int kb = 0; kb < 2; kb++)
#pragma unroll
        for (int dc = 0; dc < 4; dc++)
          kfr[kb][dc] = *reinterpret_cast<const bf16x8*>(
              uK + (kb * 32 + l31) * 64 + (((2 * dc + h) ^ e) * 8));
#pragma unroll
      for (int dt = 0; dt < 2; dt++)
#pragma unroll
        for (int kb = 0; kb < 2; kb++)
#pragma unroll
          for (int kc = 0; kc < 2; kc++)
            vfr[dt][kb][kc] = *reinterpret_cast<const bf16x8*>(
                uV + (dt * 32 + l31) * 64 + (((4 * kb + 2 * kc + h) ^ e) * 8));

      // ---- async DMA next 128-key tile into other buffer (drained at loop barrier) --
      if (sub == 0 && kt + 128 < 2048) {
        const int nb = cur ^ 1;
        STAGE_SUB(kt + 128, nb, 0);
        STAGE_SUB(kt + 192, nb, 1);
      }

      // ---- batched QK^T: all 16 MFMAs, 4 independent chains ----
      f32x16 s4[4];   // g = kb*2 + j  (static indexing only)
      __builtin_amdgcn_s_setprio(1);
#pragma unroll
      for (int g = 0; g < 4; g++) {
        const int kb = g >> 1, j = g & 1;
        f32x16 s = {};
#pragma unroll
        for (int dc = 0; dc < 4; dc++)
          s = __builtin_amdgcn_mfma_f32_32x32x16_bf16(kfr[kb][dc], qf[j][dc], s, 0, 0, 0);
        s4[g] = s;
      }
      __builtin_amdgcn_s_setprio(0);

      // ---- softmax + PV per group; group g overlaps group g-1's PV ----
#pragma unroll
      for (int g = 0; g < 4; g++) {
        const int kb = g >> 1, j = g & 1;
        float p[16];
#pragma unroll
        for (int i = 0; i < 16; i++) p[i] = fast_exp2(s4[g][i]);
#pragma unroll
        for (int i = 0; i < 16; i += 2) { ls[j][0] += p[i]; ls[j][1] += p[i + 1]; }
        uint32_t pk[4][2];
#pragma unroll
        for (int rq = 0; rq < 4; rq++) {
          pk[rq][0] = pack_bf16(p[rq * 4 + 0], p[rq * 4 + 1]);
          pk[rq][1] = pack_bf16(p[rq * 4 + 2], p[rq * 4 + 3]);
        }
        uint4 b0, b1;
        plswap(pk[0][0], pk[1][0], b0.x, b0.z);
        plswap(pk[0][1], pk[1][1], b0.y, b0.w);
        plswap(pk[2][0], pk[3][0], b1.x, b1.z);
        plswap(pk[2][1], pk[3][1], b1.y, b1.w);
        union { uint4 u; bf16x8 v; } bf0, bf1;
        bf0.u = b0; bf1.u = b1;
        __builtin_amdgcn_s_setprio(1);
#pragma unroll
        for (int dt = 0; dt < 2; dt++) {
          oacc[j][dt] = __builtin_amdgcn_mfma_f32_32x32x16_bf16(vfr[dt][kb][0], bf0.v, oacc[j][dt], 0, 0, 0);
          oacc[j][dt] = __builtin_amdgcn_mfma_f32_32x32x16_bf16(vfr[dt][kb][1], bf1.v, oacc[j][dt], 0, 0, 0);
        }
        __builtin_amdgcn_s_setprio(0);
      }
    }

    __syncthreads();   // joins: frag reads done (lgkm), next-tile DMA done (vmcnt)
    cur ^= 1;
  }
#undef STAGE_SUB

  const int b = bh >> 4, hd = bh & 15;
  u16* dst = Oout + (size_t)b * 2048 * 1024 + (size_t)hd * 64;
#pragma unroll
  for (int j = 0; j < 2; j++) {
    float lsum = ls[j][0] + ls[j][1];
    lsum += __shfl_xor(lsum, 32, 64);
    float inv = __builtin_amdgcn_rcpf(lsum);
    const size_t qrow = (size_t)(q0 + wave * 64 + j * 32 + l31) * 1024;
#pragma unroll
    for (int dt = 0; dt < 2; dt++)
#pragma unroll
      for (int rq = 0; rq < 4; rq++) {
        uint2 o;
        o.x = pack_bf16(oacc[j][dt][rq * 4 + 0] * inv, oacc[j][dt][rq * 4 + 1] * inv);
        o.y = pack_bf16(oacc[j][dt][rq * 4 + 2] * inv, oacc[j][dt][rq * 4 + 3] * inv);
        *reinterpret_cast<uint2*>(dst + qrow + dt * 32 + rq * 8 + h * 4) = o;
      }
  }
}

extern "C" void kernel_launch(void* const* d_in, const int* in_sizes, int n_in,
                              void* d_out, int out_size, void* d_ws, size_t ws_size,
                              hipStream_t stream) {
  (void)in_sizes; (void)n_in; (void)out_size; (void)ws_size;
  const float* z  = (const float*)d_in[0];
  const float* wq = (const float*)d_in[1];
  const float* wk = (const float*)d_in[2];
  const float* wv = (const float*)d_in[3];
  const float* wo = (const float*)d_in[4];
  const float* bo = (const float*)d_in[5];
  float* out = (float*)d_out;

  // workspace layout (72 MiB):
  char* ws = (char*)d_ws;
  u16* zb   = (u16*)(ws);                          // 16 MiB  z bf16 [8192][1024]; reused as attn_out
  u16* bqkv = (u16*)(ws + (16ull << 20));          // 6 MiB   W_qkv^T [3072][1024]
  u16* wot  = (u16*)(ws + (22ull << 20));          // 2 MiB   W_o^T   [1024][1024]
  u16* Qb   = (u16*)(ws + (24ull << 20));          // 16 MiB  [64][2048][64]
  u16* Kb   = (u16*)(ws + (40ull << 20));          // 16 MiB  [64][2048][64]
  u16* Vtb  = (u16*)(ws + (56ull << 20));          // 16 MiB  [64][64][2048] (written by GEMM)
  u16* Ob   = zb;                                  // attn_out [8192][1024]

  prep_kernel<<<12288, 256, 0, stream>>>(z, zb, wq, wk, wv, wo, bqkv, wot);
  gemm256_kernel<<<dim3(12, 32), 512, 0, stream>>>(zb, bqkv, Qb, Kb, Vtb);
  attn_kernel<<<dim3(64, 8), 256, 0, stream>>>(Qb, Kb, Vtb, Ob);
  gemm_bt64_kernel<<<dim3(16, 64), 256, 0, stream>>>(Ob, wot, out, bo);
}

// Round 10
// 278.294 us; speedup vs baseline: 1.0358x; 1.0258x over previous
//
#include <hip/hip_runtime.h>
#include <hip/hip_bf16.h>
#include <stdint.h>

typedef unsigned short u16;
typedef __attribute__((ext_vector_type(8))) short bf16x8;
typedef __attribute__((ext_vector_type(4))) float f32x4;
typedef __attribute__((ext_vector_type(16))) float f32x16;

static __device__ inline u16 f2bf(float f) {
  union { float f; uint32_t u; } v; v.f = f;
  uint32_t u = v.u;
  u += 0x7fffu + ((u >> 16) & 1);   // RNE
  return (u16)(u >> 16);
}

// fast 2^x -> single v_exp_f32
static __device__ inline float fast_exp2(float x) {
#if __has_builtin(__builtin_amdgcn_exp2f)
  return __builtin_amdgcn_exp2f(x);
#else
  return __expf(x * 0.6931471805599453f);
#endif
}

// pack two fp32 -> packed bf16x2
static __device__ inline uint32_t pack_bf16(float lo, float hi) {
#if __has_builtin(__builtin_amdgcn_cvt_pk_bf16_f32)
  typedef __attribute__((ext_vector_type(2))) __bf16 bf16x2_t;
  bf16x2_t r = __builtin_amdgcn_cvt_pk_bf16_f32(lo, hi);
  union { bf16x2_t v; uint32_t u; } c; c.v = r;
  return c.u;
#else
  union { float f; uint32_t u; } a, b;
  a.f = lo; b.f = hi;
  uint32_t ua = a.u + 0x8000u;
  uint32_t ub = b.u + 0x8000u;
  return __builtin_amdgcn_perm(ub, ua, 0x07060302u);
#endif
}

// cross-half exchange: x = [a_lo | b_lo_from_partner], y = [a_hi_from_partner | b_hi]
static __device__ __forceinline__ void plswap(uint32_t a, uint32_t b,
                                              uint32_t& x, uint32_t& y) {
#if __has_builtin(__builtin_amdgcn_permlane32_swap)
  auto r = __builtin_amdgcn_permlane32_swap(a, b, false, false);
  x = (uint32_t)r[0]; y = (uint32_t)r[1];
#else
  int h = (threadIdx.x & 63) >> 5;
  uint32_t pa = (uint32_t)__shfl_xor((int)a, 32, 64);
  uint32_t pb = (uint32_t)__shfl_xor((int)b, 32, 64);
  x = h ? pb : a;
  y = h ? b : pa;
#endif
}

// async global->LDS, 16B per lane; LDS dest must be lane-contiguous (base + lane*16)
static __device__ __forceinline__ void load_lds_128(const u16* g, u16* l) {
  __builtin_amdgcn_global_load_lds((const __attribute__((address_space(1))) void*)g,
                                   (__attribute__((address_space(3))) void*)l,
                                   16, 0, 0);
}

// ---------------- fused prep: cast z fp32->bf16  +  weight transpose/cast ----------
__global__ __launch_bounds__(256) void prep_kernel(const float* __restrict__ zsrc,
                                                   u16* __restrict__ zdst,
                                                   const float* __restrict__ wq,
                                                   const float* __restrict__ wk,
                                                   const float* __restrict__ wv,
                                                   const float* __restrict__ wo,
                                                   u16* __restrict__ bqkv,
                                                   u16* __restrict__ wot) {
  const int bid = blockIdx.x;
  const int tid = threadIdx.x;
  if (bid < 8192) {
    int i = bid * 256 + tid;
    float4 v = reinterpret_cast<const float4*>(zsrc)[i];
    uint2 o;
    o.x = pack_bf16(v.x, v.y);
    o.y = pack_bf16(v.z, v.w);
    reinterpret_cast<uint2*>(zdst)[i] = o;
    return;
  }
  const int w = bid - 8192;
  const int z = w >> 10;
  const int rem = w & 1023;
  const float* src = (z == 0) ? wq : (z == 1) ? wk : (z == 2) ? wv : wo;
  u16* dst = (z < 3) ? (bqkv + (size_t)z * 1024 * 1024) : wot;
  __shared__ float tile[32][33];
  const int c0 = (rem & 31) * 32, r0 = (rem >> 5) * 32;
  const int tx = tid & 31, ty = tid >> 5;
#pragma unroll
  for (int i = 0; i < 32; i += 8)
    tile[ty + i][tx] = src[(size_t)(r0 + ty + i) * 1024 + c0 + tx];
  __syncthreads();
#pragma unroll
  for (int i = 0; i < 32; i += 8)
    dst[(size_t)(c0 + ty + i) * 1024 + r0 + tx] = f2bf(tile[tx][ty + i]);
}

// ---------------- GEMM m97 128x64 tile (output projection): C = A @ Bt^T + bias ----
// grid (16,64) = 1024 blocks = 4 blocks/CU = 16 waves/CU. LDS 12 KB, acc[4][2].
__global__ __launch_bounds__(256) void gemm_bt64_kernel(
    const u16* __restrict__ A, const u16* __restrict__ Bt,
    float* __restrict__ outC, const float* __restrict__ bias) {
  const int Kd = 1024;
  const int n0 = blockIdx.x * 64;
  const int m0 = blockIdx.y * 128;
  __shared__ __align__(16) u16 Asm[128 * 32];
  __shared__ __align__(16) u16 Bsm[64 * 32];
  const int tid = threadIdx.x;
  const int wave = tid >> 6, lane = tid & 63;
  const int quad = lane >> 4, l15 = lane & 15;
  const int wm = (wave >> 1) * 64, wn = (wave & 1) * 32;

  const int c0 = wave * 128 + lane;     // A chunks 0..511 (two per thread)
  const int c1 = c0 + 64;
  const int r0 = c0 >> 2, p0 = (c0 & 3) * 8;
  const int r1 = c1 >> 2, p1 = (c1 & 3) * 8;
  const int cB = tid;                   // B chunks 0..255 (one per thread)
  const int rB = cB >> 2, pB = (cB & 3) * 8;

  const u16* Ab = A + (size_t)m0 * Kd;
  const u16* Bb = Bt + (size_t)n0 * Kd;

  f32x4 acc[4][2] = {};

  for (int k0 = 0; k0 < Kd; k0 += 32) {
    __syncthreads();
    load_lds_128(Ab + (size_t)r0 * Kd + k0 + p0, Asm + c0 * 8);
    load_lds_128(Ab + (size_t)r1 * Kd + k0 + p1, Asm + c1 * 8);
    load_lds_128(Bb + (size_t)rB * Kd + k0 + pB, Bsm + cB * 8);
    __syncthreads();
    bf16x8 af[4], bf[2];
#pragma unroll
    for (int i = 0; i < 4; i++)
      af[i] = *reinterpret_cast<const bf16x8*>(Asm + (wm + i * 16 + l15) * 32 + quad * 8);
#pragma unroll
    for (int i = 0; i < 2; i++)
      bf[i] = *reinterpret_cast<const bf16x8*>(Bsm + (wn + i * 16 + l15) * 32 + quad * 8);
#pragma unroll
    for (int mi = 0; mi < 4; mi++)
#pragma unroll
      for (int ni = 0; ni < 2; ni++)
        acc[mi][ni] = __builtin_amdgcn_mfma_f32_16x16x32_bf16(af[mi], bf[ni], acc[mi][ni], 0, 0, 0);
  }

#pragma unroll
  for (int mi = 0; mi < 4; mi++)
#pragma unroll
    for (int ni = 0; ni < 2; ni++) {
      int n = n0 + wn + ni * 16 + l15;
      float bv = bias[n];
#pragma unroll
      for (int r = 0; r < 4; r++) {
        int m = m0 + wm + mi * 16 + quad * 4 + r;
        outC[(size_t)m * 1024 + n] = acc[mi][ni][r] + bv;
      }
    }
}

// ---------------- 256x256 8-phase GEMM (QKV projection, MODE-0 epilogue) ------------
// (round-6 measured-best configuration: single launch dim3(12,32),
// rule-#18 sched_barrier after each lgkmcnt(0), vmcnt(8) ledger)
__global__ __launch_bounds__(512, 2) void gemm256_kernel(
    const u16* __restrict__ A, const u16* __restrict__ Bt,
    u16* __restrict__ outQ, u16* __restrict__ outK, u16* __restrict__ outVt) {
  const int tid = threadIdx.x;
  const int lane = tid & 63;
  const int wave = tid >> 6;
  const int quad = lane >> 4, l15 = lane & 15;
  const int e15 = l15 & 7;
  const int wm = wave >> 2;     // 0..1 M-half
  const int wn = wave & 3;      // 0..3 N-slice

  // XCD-aware bijective swizzle (grid 12x32 = 384 blocks, 384 % 8 == 0)
  unsigned lin = blockIdx.y * gridDim.x + blockIdx.x;
  unsigned nwg = gridDim.x * gridDim.y;
  lin = (lin & 7u) * (nwg >> 3) + (lin >> 3);
  const int bx = lin % gridDim.x, by = lin / gridDim.x;
  const int n0 = bx * 256, m0 = by * 256;

  __shared__ __align__(16) u16 AsmL[2][16384];   // [buf][half*8192 + row*64 + slot*8]
  __shared__ __align__(16) u16 BsmL[2][16384];
  u16* const As_[2] = {&AsmL[0][0], &AsmL[1][0]};
  u16* const Bs_[2] = {&BsmL[0][0], &BsmL[1][0]};

  const u16* Abase = A + (size_t)m0 * 1024;
  const u16* Bbase = Bt + (size_t)n0 * 1024;

  const int awoff = wm * 8192;
  const int bwoff = (wn >> 1) * 8192 + (wn & 1) * 4096;

  f32x4 acc[8][4] = {};
  bf16x8 af[4][2], bfr[4][2];

#define STG_HALF(ldsp, gp)                                                      \
  {                                                                             \
    const int cs0 = tid, cs1 = tid + 512;                                       \
    const int r0_ = cs0 >> 3, g0_ = (((cs0 & 7) ^ (r0_ & 7)) << 3);             \
    const int r1_ = cs1 >> 3, g1_ = (((cs1 & 7) ^ (r1_ & 7)) << 3);             \
    load_lds_128((gp) + (size_t)r0_ * 1024 + g0_, (ldsp) + cs0 * 8);            \
    load_lds_128((gp) + (size_t)r1_ * 1024 + g1_, (ldsp) + cs1 * 8);            \
  }

#define PHB() do { asm volatile("" ::: "memory"); __builtin_amdgcn_s_barrier(); \
                   asm volatile("" ::: "memory"); } while (0)
#define LGKM0() do { asm volatile("s_waitcnt lgkmcnt(0)" ::: "memory");         \
                     __builtin_amdgcn_sched_barrier(0); } while (0)
#define VMC8()  asm volatile("s_waitcnt vmcnt(8)" ::: "memory")

#define RD_A(mb, B)                                                             \
  _Pragma("unroll") for (int x = 0; x < 4; x++)                                 \
  _Pragma("unroll") for (int kk = 0; kk < 2; kk++)                              \
    af[x][kk] = *reinterpret_cast<const bf16x8*>(                               \
        As_[B] + awoff + (((mb) + x) * 16 + l15) * 64 + (((quad + kk * 4) ^ e15) << 3));

#define RD_B(nb, B)                                                             \
  _Pragma("unroll") for (int x = 0; x < 2; x++)                                 \
  _Pragma("unroll") for (int kk = 0; kk < 2; kk++)                              \
    bfr[(nb) + x][kk] = *reinterpret_cast<const bf16x8*>(                       \
        Bs_[B] + bwoff + (((nb) + x) * 16 + l15) * 64 + (((quad + kk * 4) ^ e15) << 3));

#define MM(mb, nb)                                                              \
  _Pragma("unroll") for (int kk = 0; kk < 2; kk++)                              \
  _Pragma("unroll") for (int x = 0; x < 4; x++)                                 \
  _Pragma("unroll") for (int y = 0; y < 2; y++)                                 \
    acc[(mb) + x][(nb) + y] = __builtin_amdgcn_mfma_f32_16x16x32_bf16(          \
        af[x][kk], bfr[(nb) + y][kk], acc[(mb) + x][(nb) + y], 0, 0, 0);

#define TILE4(B, KS)                                                            \
  RD_A(0, B); RD_B(0, B);                                                       \
  PHB(); LGKM0(); __builtin_amdgcn_s_setprio(1); MM(0, 0);                      \
  __builtin_amdgcn_s_setprio(0); PHB();                                         \
  RD_B(2, B);                                                                   \
  PHB(); LGKM0(); __builtin_amdgcn_s_setprio(1); MM(0, 2);                      \
  __builtin_amdgcn_s_setprio(0); PHB();                                         \
  RD_A(4, B);                                                                   \
  STG_HALF(Bs_[B], Bbase + (KS)); STG_HALF(Bs_[B] + 8192, Bbase + 128 * 1024 + (KS)); \
  PHB(); LGKM0(); __builtin_amdgcn_s_setprio(1); MM(4, 0);                      \
  __builtin_amdgcn_s_setprio(0); PHB();                                         \
  STG_HALF(As_[B], Abase + (KS)); STG_HALF(As_[B] + 8192, Abase + 128 * 1024 + (KS)); \
  PHB(); __builtin_amdgcn_s_setprio(1); MM(4, 2);                               \
  __builtin_amdgcn_s_setprio(0); VMC8(); PHB();

  // prologue: tile0 -> buf0 (oldest 8 loads), tile1 -> buf1
  STG_HALF(As_[0], Abase);      STG_HALF(As_[0] + 8192, Abase + 128 * 1024);
  STG_HALF(Bs_[0], Bbase);      STG_HALF(Bs_[0] + 8192, Bbase + 128 * 1024);
  STG_HALF(As_[1], Abase + 64); STG_HALF(As_[1] + 8192, Abase + 128 * 1024 + 64);
  STG_HALF(Bs_[1], Bbase + 64); STG_HALF(Bs_[1] + 8192, Bbase + 128 * 1024 + 64);
  VMC8(); PHB();

#pragma unroll 1
  for (int it = 0; it < 8; ++it) {
    int t2 = it * 2 + 2; if (t2 > 15) t2 = 15;   // clamped: tail re-stages valid
    int t3 = it * 2 + 3; if (t3 > 15) t3 = 15;   // data into dead slots (never read)
    const int k2 = t2 * 64, k3 = t3 * 64;
    TILE4(0, k2);
    TILE4(1, k3);
  }

  // -------- MODE-0 epilogue: split Q / K / Vt --------
  const int which = (n0 + wn * 64) >> 10;
#pragma unroll
  for (int mi = 0; mi < 8; mi++)
#pragma unroll
    for (int ni = 0; ni < 4; ni++) {
      int n = n0 + wn * 64 + ni * 16 + l15;
      int hn = n & 1023;
      int hh = hn >> 6, dim = hn & 63;
      if (which == 2) {
        int m = m0 + wm * 128 + mi * 16 + quad * 4;
        int b = m >> 11, tok = m & 2047;
        uint2 pk;
        pk.x = pack_bf16(acc[mi][ni][0], acc[mi][ni][1]);
        pk.y = pack_bf16(acc[mi][ni][2], acc[mi][ni][3]);
        *reinterpret_cast<uint2*>(outVt + ((size_t)(b * 16 + hh) * 64 + dim) * 2048 + tok) = pk;
      } else {
        u16* dst = (which == 0) ? outQ : outK;
        float qscale = (which == 0) ? 0.1803368801111204f : 1.0f; // 0.125*log2(e)
#pragma unroll
        for (int r = 0; r < 4; r++) {
          int m = m0 + wm * 128 + mi * 16 + quad * 4 + r;
          int b = m >> 11, tok = m & 2047;
          dst[(((size_t)(b * 16 + hh)) * 2048 + tok) * 64 + dim] = f2bf(acc[mi][ni][r] * qscale);
        }
      }
    }
#undef STG_HALF
#undef PHB
#undef LGKM0
#undef VMC8
#undef RD_A
#undef RD_B
#undef MM
#undef TILE4
}

// ---------------- flash attention: 64 q/wave, batched QK, permlane exchange --------
// ROUND-6 MEASURED-BEST VERSION (88.8 us). Session evidence that this is a local
// optimum of the decomposition: kv-split 16-waves/CU (+6.6 us), manual 3-buffer
// vmcnt pipeline (+10.7 us), KVBLK=128 barrier-halving (+5.5 us) all regressed.
// The ~20% uncovered cycles (MfmaUtil 33 + VALUBusy 46) are dependency bubbles
// at the grid-pinned 2 waves/SIMD; compiler-managed sync + 2-block co-residency
// covers the DMA drain better than any manual schedule tried (m131-m141 lesson).
__global__ __launch_bounds__(256, 2) void attn_kernel(const u16* __restrict__ Q,
                                                      const u16* __restrict__ K,
                                                      const u16* __restrict__ Vt,
                                                      u16* __restrict__ Oout) {
  const int bh = blockIdx.x;
  const int q0 = blockIdx.y * 256;
  const int tid = threadIdx.x;
  const int wave = tid >> 6, lane = tid & 63;
  const int l31 = lane & 31, h = lane >> 5;
  const int e = l31 & 7;

  __shared__ __align__(16) u16 Kb2[2][4096];   // [64 rows][64], swizzled chunks
  __shared__ __align__(16) u16 Vb2[2][4096];

  const u16* Qg = Q + ((size_t)bh * 2048 + q0 + wave * 64) * 64;
  const u16* Kg = K + (size_t)bh * 2048 * 64;
  const u16* Vg = Vt + (size_t)bh * 64 * 2048;

  bf16x8 qf[2][4];
#pragma unroll
  for (int j = 0; j < 2; j++)
#pragma unroll
    for (int dc = 0; dc < 4; dc++)
      qf[j][dc] = *reinterpret_cast<const bf16x8*>(
          Qg + (size_t)(j * 32 + l31) * 64 + dc * 16 + h * 8);

  const int s0 = tid, s1 = tid + 256;
  const int sr0 = s0 >> 3, sg0 = ((s0 & 7) ^ (sr0 & 7)) * 8;
  const int sr1 = s1 >> 3, sg1 = ((s1 & 7) ^ (sr1 & 7)) * 8;

  load_lds_128(Kg + (size_t)sr0 * 64 + sg0, &Kb2[0][s0 * 8]);
  load_lds_128(Kg + (size_t)sr1 * 64 + sg1, &Kb2[0][s1 * 8]);
  load_lds_128(Vg + (size_t)sr0 * 2048 + sg0, &Vb2[0][s0 * 8]);
  load_lds_128(Vg + (size_t)sr1 * 2048 + sg1, &Vb2[0][s1 * 8]);
  __syncthreads();   // tile 0 resident

  float ls[2][2] = {};
  f32x16 oacc[2][2] = {};   // [j][dt]
  int cur = 0;

  for (int kt = 0; kt < 2048; kt += 64) {
    const u16* uK = &Kb2[cur][0];
    const u16* uV = &Vb2[cur][0];

    bf16x8 kfr[2][4], vfr[2][2][2];
#pragma unroll
    for (int kb = 0; kb < 2; kb++)
#pragma unroll
      for (int dc = 0; dc < 4; dc++)
        kfr[kb][dc] = *reinterpret_cast<const bf16x8*>(
            uK + (kb * 32 + l31) * 64 + (((2 * dc + h) ^ e) * 8));
#pragma unroll
    for (int dt = 0; dt < 2; dt++)
#pragma unroll
      for (int kb = 0; kb < 2; kb++)
#pragma unroll
        for (int kc = 0; kc < 2; kc++)
          vfr[dt][kb][kc] = *reinterpret_cast<const bf16x8*>(
              uV + (dt * 32 + l31) * 64 + (((4 * kb + 2 * kc + h) ^ e) * 8));

    if (kt + 64 < 2048) {
      const int nb = cur ^ 1;
      load_lds_128(Kg + (size_t)(kt + 64 + sr0) * 64 + sg0, &Kb2[nb][s0 * 8]);
      load_lds_128(Kg + (size_t)(kt + 64 + sr1) * 64 + sg1, &Kb2[nb][s1 * 8]);
      load_lds_128(Vg + (size_t)sr0 * 2048 + kt + 64 + sg0, &Vb2[nb][s0 * 8]);
      load_lds_128(Vg + (size_t)sr1 * 2048 + kt + 64 + sg1, &Vb2[nb][s1 * 8]);
    }

    // ---- batched QK^T: all 16 MFMAs, 4 independent chains ----
    f32x16 s4[4];   // g = kb*2 + j  (static indexing only)
    __builtin_amdgcn_s_setprio(1);
#pragma unroll
    for (int g = 0; g < 4; g++) {
      const int kb = g >> 1, j = g & 1;
      f32x16 s = {};
#pragma unroll
      for (int dc = 0; dc < 4; dc++)
        s = __builtin_amdgcn_mfma_f32_32x32x16_bf16(kfr[kb][dc], qf[j][dc], s, 0, 0, 0);
      s4[g] = s;
    }
    __builtin_amdgcn_s_setprio(0);

    // ---- softmax + PV per group; group g overlaps group g-1's PV ----
#pragma unroll
    for (int g = 0; g < 4; g++) {
      const int kb = g >> 1, j = g & 1;
      float p[16];
#pragma unroll
      for (int i = 0; i < 16; i++) p[i] = fast_exp2(s4[g][i]);
#pragma unroll
      for (int i = 0; i < 16; i += 2) { ls[j][0] += p[i]; ls[j][1] += p[i + 1]; }
      uint32_t pk[4][2];
#pragma unroll
      for (int rq = 0; rq < 4; rq++) {
        pk[rq][0] = pack_bf16(p[rq * 4 + 0], p[rq * 4 + 1]);
        pk[rq][1] = pack_bf16(p[rq * 4 + 2], p[rq * 4 + 3]);
      }
      uint4 b0, b1;
      plswap(pk[0][0], pk[1][0], b0.x, b0.z);
      plswap(pk[0][1], pk[1][1], b0.y, b0.w);
      plswap(pk[2][0], pk[3][0], b1.x, b1.z);
      plswap(pk[2][1], pk[3][1], b1.y, b1.w);
      union { uint4 u; bf16x8 v; } bf0, bf1;
      bf0.u = b0; bf1.u = b1;
      __builtin_amdgcn_s_setprio(1);
#pragma unroll
      for (int dt = 0; dt < 2; dt++) {
        oacc[j][dt] = __builtin_amdgcn_mfma_f32_32x32x16_bf16(vfr[dt][kb][0], bf0.v, oacc[j][dt], 0, 0, 0);
        oacc[j][dt] = __builtin_amdgcn_mfma_f32_32x32x16_bf16(vfr[dt][kb][1], bf1.v, oacc[j][dt], 0, 0, 0);
      }
      __builtin_amdgcn_s_setprio(0);
    }

    __syncthreads();
    cur ^= 1;
  }

  const int b = bh >> 4, hd = bh & 15;
  u16* dst = Oout + (size_t)b * 2048 * 1024 + (size_t)hd * 64;
#pragma unroll
  for (int j = 0; j < 2; j++) {
    float lsum = ls[j][0] + ls[j][1];
    lsum += __shfl_xor(lsum, 32, 64);
    float inv = __builtin_amdgcn_rcpf(lsum);
    const size_t qrow = (size_t)(q0 + wave * 64 + j * 32 + l31) * 1024;
#pragma unroll
    for (int dt = 0; dt < 2; dt++)
#pragma unroll
      for (int rq = 0; rq < 4; rq++) {
        uint2 o;
        o.x = pack_bf16(oacc[j][dt][rq * 4 + 0] * inv, oacc[j][dt][rq * 4 + 1] * inv);
        o.y = pack_bf16(oacc[j][dt][rq * 4 + 2] * inv, oacc[j][dt][rq * 4 + 3] * inv);
        *reinterpret_cast<uint2*>(dst + qrow + dt * 32 + rq * 8 + h * 4) = o;
      }
  }
}

extern "C" void kernel_launch(void* const* d_in, const int* in_sizes, int n_in,
                              void* d_out, int out_size, void* d_ws, size_t ws_size,
                              hipStream_t stream) {
  (void)in_sizes; (void)n_in; (void)out_size; (void)ws_size;
  const float* z  = (const float*)d_in[0];
  const float* wq = (const float*)d_in[1];
  const float* wk = (const float*)d_in[2];
  const float* wv = (const float*)d_in[3];
  const float* wo = (const float*)d_in[4];
  const float* bo = (const float*)d_in[5];
  float* out = (float*)d_out;

  // workspace layout (72 MiB):
  char* ws = (char*)d_ws;
  u16* zb   = (u16*)(ws);                          // 16 MiB  z bf16 [8192][1024]; reused as attn_out
  u16* bqkv = (u16*)(ws + (16ull << 20));          // 6 MiB   W_qkv^T [3072][1024]
  u16* wot  = (u16*)(ws + (22ull << 20));          // 2 MiB   W_o^T   [1024][1024]
  u16* Qb   = (u16*)(ws + (24ull << 20));          // 16 MiB  [64][2048][64]
  u16* Kb   = (u16*)(ws + (40ull << 20));          // 16 MiB  [64][2048][64]
  u16* Vtb  = (u16*)(ws + (56ull << 20));          // 16 MiB  [64][64][2048] (written by GEMM)
  u16* Ob   = zb;                                  // attn_out [8192][1024]

  prep_kernel<<<12288, 256, 0, stream>>>(z, zb, wq, wk, wv, wo, bqkv, wot);
  gemm256_kernel<<<dim3(12, 32), 512, 0, stream>>>(zb, bqkv, Qb, Kb, Vtb);
  attn_kernel<<<dim3(64, 8), 256, 0, stream>>>(Qb, Kb, Vtb, Ob);
  gemm_bt64_kernel<<<dim3(16, 64), 256, 0, stream>>>(Ob, wot, out, bo);
}